// Round 4
// baseline (517.408 us; speedup 1.0000x reference)
//
#include <hip/hip_runtime.h>
#include <hip/hip_bf16.h>

#define NN 50000
#define NE 1600000
#define FF 128
#define CC 16
#define NB ((NN + 63) / 64)       // 782 dst-buckets of 64 nodes
#define NBLK 256                  // partition blocks for the sort (all CUs)
#define CH ((NE + NBLK - 1) / NBLK)   // 6250 edges per partition block

using bf16 = __hip_bfloat16;
using bf16x8 = __attribute__((ext_vector_type(8))) short;   // 8 bf16 = 4 VGPRs
using f32x4  = __attribute__((ext_vector_type(4))) float;

// Runtime-dtype load: isbf selects bf16 vs f32 interpretation of p.
static __device__ __forceinline__ float ldf(const void* p, int i, int isbf){
    return isbf ? __bfloat162float(((const bf16*)p)[i]) : ((const float*)p)[i];
}
static __device__ __forceinline__ float bflo(unsigned u){
    union{unsigned x; float f;} c; c.x = u << 16; return c.f;
}
static __device__ __forceinline__ float bfhi(unsigned u){
    union{unsigned x; float f;} c; c.x = u & 0xFFFF0000u; return c.f;
}
static __device__ __forceinline__ unsigned short f2bfu(float v){
    bf16 b = __float2bfloat16(v);
    union{bf16 b; unsigned short u;} c; c.b = b; return c.u;
}

// ---------------- fused prep: dtype detect + bcounts zero + W1/W2/W3 transpose->bf16 ----------------
__global__ __launch_bounds__(256) void k_prep(const unsigned short* __restrict__ featu,
                                              const void* __restrict__ W1, const void* __restrict__ W2,
                                              const void* __restrict__ W3, int* __restrict__ dflag,
                                              int* __restrict__ bcounts, unsigned short* __restrict__ wtg){
    __shared__ int cnt;
    const int t = threadIdx.x;
    if (t == 0) cnt = 0;
    __syncthreads();
    unsigned short lo = featu[2 * t];
    int e = (lo >> 7) & 0xFF;
    if (e >= 117 && e <= 137) atomicAdd(&cnt, 1);
    __syncthreads();
    const int isbf = (cnt >= 128) ? 1 : 0;   // 1 => bf16 inputs
    int idx = blockIdx.x * 256 + t;
    if (idx == 0) *dflag = isbf;
    if (idx < NB) bcounts[idx] = 0;
    if (idx < 32768){
        int l = idx >> 14;                   // 0: W1, 1: W2
        int e2 = idx & 16383;
        int f = e2 >> 7, k = e2 & 127;
        const void* W = l ? W2 : W1;
        wtg[idx] = f2bfu(ldf(W, k * FF + f, isbf));
    } else if (idx < 34816){
        int e2 = idx - 32768;                // W3t: 16x128
        int f = e2 >> 7, k = e2 & 127;
        wtg[idx] = f2bfu(ldf(W3, k * CC + f, isbf));
    }
}

// ---------------- CSR build: hierarchical counting sort by dst ----------------

__global__ __launch_bounds__(256) void k_bcount(const int* __restrict__ dst, int* __restrict__ bcounts,
                                                int* __restrict__ bh){
    __shared__ int hist[NB];
    const int t = threadIdx.x, b = blockIdx.x;
    for (int i = t; i < NB; i += 256) hist[i] = 0;
    __syncthreads();
    const int beg = b * CH, end = (beg + CH < NE) ? beg + CH : NE;
    for (int i = beg + t; i < end; i += 256){
        int d = dst[i];
        if ((unsigned)d >= NN) d = 0;
        atomicAdd(&hist[d >> 6], 1);
    }
    __syncthreads();
    for (int k = t; k < NB; k += 256){
        int v = hist[k];
        bh[k * NBLK + b] = v;
        if (v) atomicAdd(&bcounts[k], v);
    }
}

__global__ __launch_bounds__(256) void k_bscan(const int* __restrict__ bcounts, int* __restrict__ bbase,
                                               int* __restrict__ rowptr){
    __shared__ int s[256];
    const int t = threadIdx.x;
    constexpr int PT = (NB + 255) / 256;   // 4
    int loc[PT];
    int sum = 0;
    #pragma unroll
    for (int i = 0; i < PT; i++){
        int idx = t * PT + i;
        int v = (idx < NB) ? bcounts[idx] : 0;
        loc[i] = sum;
        sum += v;
    }
    s[t] = sum; __syncthreads();
    for (int off = 1; off < 256; off <<= 1){
        int x = (t >= off) ? s[t - off] : 0;
        __syncthreads();
        s[t] += x;
        __syncthreads();
    }
    int base = (t > 0) ? s[t - 1] : 0;
    #pragma unroll
    for (int i = 0; i < PT; i++){
        int idx = t * PT + i;
        if (idx < NB) bbase[idx] = base + loc[i];
    }
    if (t == 255){
        bbase[NB] = s[255];      // == NE
        rowptr[NN] = s[255];
    }
}

// Per-bucket offsets: wave-per-bucket shfl scan over the 256 per-block counts (4/lane).
__global__ __launch_bounds__(256) void k_boffset(const int* __restrict__ bbase, int* __restrict__ bh){
    int k = blockIdx.x * 4 + (threadIdx.x >> 6);
    int lane = threadIdx.x & 63;
    if (k >= NB) return;
    int v[4];
    int s = 0;
    #pragma unroll
    for (int i = 0; i < 4; i++){
        v[i] = bh[k * NBLK + 4 * lane + i];
        s += v[i];
    }
    int tot = s;
    #pragma unroll
    for (int off = 1; off < 64; off <<= 1){
        int x = __shfl_up(s, off);
        if (lane >= off) s += x;
    }
    int run = bbase[k] + s - tot;   // exclusive prefix of per-lane sums
    #pragma unroll
    for (int i = 0; i < 4; i++){
        bh[k * NBLK + 4 * lane + i] = run;
        run += v[i];
    }
}

__global__ __launch_bounds__(256) void k_bucket(const int* __restrict__ src, const int* __restrict__ dst,
                                                const int* __restrict__ bh, unsigned* __restrict__ bpairs){
    __shared__ int cur[NB];
    const int t = threadIdx.x, b = blockIdx.x;
    for (int k = t; k < NB; k += 256) cur[k] = bh[k * NBLK + b];
    __syncthreads();
    const int beg = b * CH, end = (beg + CH < NE) ? beg + CH : NE;
    for (int i = beg + t; i < end; i += 256){
        int s = src[i];
        int d = dst[i];
        if ((unsigned)s >= NN) s = 0;
        if ((unsigned)d >= NN) d = 0;
        int p = atomicAdd(&cur[d >> 6], 1);
        if ((unsigned)p < NE) bpairs[p] = (unsigned)s | ((unsigned)(d & 63) << 16);
    }
}

__global__ __launch_bounds__(256) void k_bsort(const unsigned* __restrict__ bpairs, const int* __restrict__ bbase,
                                               int* __restrict__ rowptr, int* __restrict__ csrsrc){
    __shared__ int cnt[64];
    __shared__ int cur[64];
    const int t = threadIdx.x;
    const int b = blockIdx.x;
    const int base = bbase[b];
    const int endb = bbase[b + 1];
    if (t < 64) cnt[t] = 0;
    __syncthreads();
    for (int i = base + t; i < endb; i += 256)
        atomicAdd(&cnt[bpairs[i] >> 16], 1);
    __syncthreads();
    if (t < 64){   // wave 0 exactly: 64-lane exclusive scan via shfl
        int v = cnt[t];
        int inc = v;
        #pragma unroll
        for (int off = 1; off < 64; off <<= 1){
            int x = __shfl_up(inc, off);
            if (t >= off) inc += x;
        }
        int excl = inc - v;
        cur[t] = excl;
        int d = b * 64 + t;
        if (d < NN) rowptr[d] = base + excl;
    }
    __syncthreads();
    for (int i = base + t; i < endb; i += 256){
        unsigned pr = bpairs[i];
        int p = atomicAdd(&cur[pr >> 16], 1);
        csrsrc[base + p] = (int)(pr & 0xFFFFu);
    }
}

// ---------------- MFMA GEMM (layers 1-2), LDS-FREE ----------------
// MODE 0: layer-1 — X is node-major input feat (f32 or bf16 per dflag).
// MODE 1: layer-2 — X is pair-major bf16 hidden state hP[p][node][32].
// Output ft is written PAIR-MAJOR: ftP[p][node][32] (p = feature-pair slice 0..3),
// so the sliced aggregation kernel gets a contiguous 64B row-slice per (p, node).

template<int MODE>
__global__ __launch_bounds__(256) void k_mgemm(const void* __restrict__ X, const unsigned short* __restrict__ wtg,
                                               const void* __restrict__ al, const void* __restrict__ ar,
                                               const int* __restrict__ dflag, unsigned short* __restrict__ ftP,
                                               float* __restrict__ el, float* __restrict__ er){
    const int isbf = *dflag;
    const int t  = threadIdx.x;
    const int n0 = blockIdx.x * 64;
    const int wv = t >> 6;
    const int lane = t & 63;
    const int quad = lane >> 4;
    const int mcol = lane & 15;
    const int row = n0 + wv * 16 + mcol;
    const int rc  = (row < NN) ? row : 0;   // clamped A row

    bf16x8 afr[4];
    if (MODE == 0 && !isbf){
        const float* xr = (const float*)X + rc * FF + quad * 8;
        #pragma unroll
        for (int kt = 0; kt < 4; kt++){
            float4 a = *(const float4*)(xr + kt * 32);
            float4 b = *(const float4*)(xr + kt * 32 + 4);
            union { bf16x8 v; unsigned u[4]; } c;
            c.u[0] = (unsigned)f2bfu(a.x) | ((unsigned)f2bfu(a.y) << 16);
            c.u[1] = (unsigned)f2bfu(a.z) | ((unsigned)f2bfu(a.w) << 16);
            c.u[2] = (unsigned)f2bfu(b.x) | ((unsigned)f2bfu(b.y) << 16);
            c.u[3] = (unsigned)f2bfu(b.z) | ((unsigned)f2bfu(b.w) << 16);
            afr[kt] = c.v;
        }
    } else if (MODE == 0){
        const unsigned short* xr = (const unsigned short*)X + rc * FF + quad * 8;
        #pragma unroll
        for (int kt = 0; kt < 4; kt++)
            afr[kt] = *(const bf16x8*)(xr + kt * 32);
    } else {
        // pair-major bf16: feats q8..q8+7 live at hP[(q8>>5)][rc][q8&31]
        #pragma unroll
        for (int kt = 0; kt < 4; kt++){
            int q8 = quad * 8 + kt * 32;
            const unsigned short* xr = (const unsigned short*)X + ((size_t)(q8 >> 5) * NN + rc) * 32 + (q8 & 31);
            afr[kt] = *(const bf16x8*)xr;
        }
    }

    float elp[4] = {0.f,0.f,0.f,0.f}, erp[4] = {0.f,0.f,0.f,0.f};

    #pragma unroll
    for (int f = 0; f < 8; f++){
        f32x4 acc = {0.f, 0.f, 0.f, 0.f};
        const unsigned short* wr = wtg + (f * 16 + mcol) * FF + quad * 8;
        #pragma unroll
        for (int kt = 0; kt < 4; kt++){
            bf16x8 bfr = *(const bf16x8*)(wr + kt * 32);
            acc = __builtin_amdgcn_mfma_f32_16x16x32_bf16(afr[kt], bfr, acc, 0, 0, 0);
        }
        int col = f * 16 + mcol;
        float alv = ldf(al, col, isbf);
        float arv = ldf(ar, col, isbf);
        #pragma unroll
        for (int reg = 0; reg < 4; reg++){
            int node = n0 + wv * 16 + quad * 4 + reg;
            float v = acc[reg];
            if (node < NN)
                ftP[((size_t)(f >> 1) * NN + node) * 32 + (f & 1) * 16 + mcol] = f2bfu(v);
            elp[reg] += v * alv;
            erp[reg] += v * arv;
        }
    }

    #pragma unroll
    for (int reg = 0; reg < 4; reg++){
        float pl = elp[reg], pr = erp[reg];
        #pragma unroll
        for (int off = 1; off < 16; off <<= 1){
            pl += __shfl_xor(pl, off);
            pr += __shfl_xor(pr, off);
        }
        int node = n0 + wv * 16 + quad * 4 + reg;
        if (mcol == 0 && node < NN){ el[node] = pl; er[node] = pr; }
    }
}

// ---------------- MFMA GEMM (layer 3): ft3 = hP(pair-major bf16) @ W3, f32 node-major out ----------------

__global__ __launch_bounds__(256) void k_mgemm3(const void* __restrict__ X, const unsigned short* __restrict__ wt3g,
                                                const void* __restrict__ al, const void* __restrict__ ar,
                                                const int* __restrict__ dflag, float* __restrict__ ft,
                                                float* __restrict__ el, float* __restrict__ er){
    const int isbf = *dflag;
    const int t  = threadIdx.x;
    const int n0 = blockIdx.x * 64;
    const int wv = t >> 6;
    const int lane = t & 63;
    const int quad = lane >> 4;
    const int mcol = lane & 15;
    const int row = n0 + wv * 16 + mcol;
    const int rc  = (row < NN) ? row : 0;

    const unsigned short* wr = wt3g + mcol * FF + quad * 8;

    f32x4 acc = {0.f, 0.f, 0.f, 0.f};
    #pragma unroll
    for (int kt = 0; kt < 4; kt++){
        int q8 = quad * 8 + kt * 32;
        const unsigned short* xr = (const unsigned short*)X + ((size_t)(q8 >> 5) * NN + rc) * 32 + (q8 & 31);
        bf16x8 afr = *(const bf16x8*)xr;
        bf16x8 bfr = *(const bf16x8*)(wr + kt * 32);
        acc = __builtin_amdgcn_mfma_f32_16x16x32_bf16(afr, bfr, acc, 0, 0, 0);
    }

    float alv = ldf(al, mcol, isbf);
    float arv = ldf(ar, mcol, isbf);
    #pragma unroll
    for (int reg = 0; reg < 4; reg++){
        int node = n0 + wv * 16 + quad * 4 + reg;
        float v = acc[reg];
        if (node < NN) ft[node * CC + mcol] = v;
        float pl = v * alv, pr = v * arv;
        #pragma unroll
        for (int off = 1; off < 16; off <<= 1){
            pl += __shfl_xor(pl, off);
            pr += __shfl_xor(pr, off);
        }
        if (mcol == 0 && node < NN){ el[node] = pl; er[node] = pr; }
    }
}

// ---------------- Weight prepass: w_e = exp(leaky(el[src]+er[dst])) (no max-sub; f32-safe range), ----------------
// ---------------- per-node inv-sum written back into er[n]. 8 lanes per node. ----------------

__global__ __launch_bounds__(256) void k_wnorm(const float* __restrict__ el, float* __restrict__ er,
                                               const int* __restrict__ rowptr, const int* __restrict__ csrsrc,
                                               float* __restrict__ wcsr){
    const int t = threadIdx.x;
    const int n = blockIdx.x * 32 + (t >> 3);
    if (n >= NN) return;
    const int sub = t & 7;
    int beg = rowptr[n], end = rowptr[n + 1];
    beg = (beg < 0) ? 0 : (beg > NE ? NE : beg);
    end = (end < beg) ? beg : (end > NE ? NE : end);
    const float erd = er[n];
    float sum = 0.f;
    for (int i = beg + sub; i < end; i += 8){
        int s = csrsrc[i];
        if ((unsigned)s >= NN) s = 0;
        float e = el[s] + erd;
        e = (e >= 0.f) ? e : 0.2f * e;
        float ex = __expf(e);
        wcsr[i] = ex;
        sum += ex;
    }
    sum += __shfl_xor(sum, 1);
    sum += __shfl_xor(sum, 2);
    sum += __shfl_xor(sum, 4);
    if (sub == 0) er[n] = 1.f / ((sum > 0.f) ? sum : 1.f);
}

// ---------------- Sliced aggregation (128 feats, pair-major bf16 ft) ----------------
// Each block handles ONE 32-feature pair-slice (p = blockIdx&3) for 4 dst nodes
// (grp = blockIdx>>2). A slice of the table is 3.2MB -> fits a 4MB per-XCD L2,
// and blockIdx round-robin over XCDs pins each slice to fixed XCDs, so the random
// row gather becomes L2-resident instead of ~3TB/s L3-random traffic.
// Wave layout: g = lane>>4 picks one of 4 edges per sub-batch, c = lane&15 picks
// the uint (2 bf16 feats) of the 64B slice-row. 16 edges (4 sub-batches) per iter.
// Weights precomputed by k_wnorm (wcsr, er=1/sum): no exp, no reductions here.

__global__ __launch_bounds__(256) void k_agg128(const unsigned* __restrict__ ftP, const int* __restrict__ rowptr,
                                                const int* __restrict__ csrsrc, const float* __restrict__ wcsr,
                                                const float* __restrict__ erinv, const void* __restrict__ bias,
                                                const int* __restrict__ dflag, unsigned* __restrict__ outP){
    const int isbf = *dflag;
    const int p   = blockIdx.x & 3;           // feature-pair slice (32 feats)
    const int grp = blockIdx.x >> 2;          // node group of 4
    const int lane = threadIdx.x & 63;
    const int n = grp * 4 + (threadIdx.x >> 6);
    if (n >= NN) return;
    int beg = rowptr[n], end = rowptr[n + 1];
    beg = (beg < 0) ? 0 : (beg > NE ? NE : beg);
    end = (end < beg) ? beg : (end > NE ? NE : end);

    const int g = lane >> 4;
    const int c = lane & 15;
    const unsigned* fp = ftP + (size_t)p * NN * 16;   // 16 uints (64B) per node
    float a0 = 0.f, a1 = 0.f;

    for (int j = beg; j < end; j += 16){
        #pragma unroll
        for (int q = 0; q < 4; q++){
            int iq = j + q * 4 + g;
            int cq = (iq < end) ? iq : beg;
            int s  = csrsrc[cq];
            if ((unsigned)s >= NN) s = 0;
            float w = (iq < end) ? wcsr[cq] : 0.f;
            unsigned u = fp[(unsigned)s * 16u + c];
            a0 += w * bflo(u);
            a1 += w * bfhi(u);
        }
    }

    // Combine the 4 per-group partials: lanes sharing c sum across g (lane bits 4-5).
    a0 += __shfl_xor(a0, 16); a0 += __shfl_xor(a0, 32);
    a1 += __shfl_xor(a1, 16); a1 += __shfl_xor(a1, 32);

    if (g == 0){
        float inv = erinv[n];
        int fcol = p * 32 + 2 * c;
        float o0 = fmaxf(a0 * inv + ldf(bias, fcol,     isbf), 0.f);
        float o1 = fmaxf(a1 * inv + ldf(bias, fcol + 1, isbf), 0.f);
        outP[((size_t)p * NN + n) * 16u + c] = (unsigned)f2bfu(o0) | ((unsigned)f2bfu(o1) << 16);
    }
}

// ---------------- Aggregation (16 feats, f32 ft): single-pass gather with inline softmax ----------------
// Footprint 3.2MB (L2-resident per XCD); g = lane>>2 picks one of 16 edges, c = lane&3 the float4.

__global__ __launch_bounds__(256) void k_agg16(const float* __restrict__ ftv, const float* __restrict__ el,
                                               const float* __restrict__ er, const int* __restrict__ rowptr,
                                               const int* __restrict__ csrsrc, const void* __restrict__ bias,
                                               const int* __restrict__ dflag, void* __restrict__ outp){
    const int isbf = *dflag;
    const int lane = threadIdx.x & 63;
    const int n = blockIdx.x * 4 + (threadIdx.x >> 6);
    if (n >= NN) return;
    int beg = rowptr[n], end = rowptr[n + 1];
    beg = (beg < 0) ? 0 : (beg > NE ? NE : beg);
    end = (end < beg) ? beg : (end > NE ? NE : end);
    const float erd = er[n];

    const int g = lane >> 2;     // edge slot 0..15
    const int c = lane & 3;      // float4 index within 64B row
    const float4* ftq = (const float4*)ftv;
    float a0 = 0.f, a1 = 0.f, a2 = 0.f, a3 = 0.f;
    float lsum = 0.f;

    for (int j = beg; j < end; j += 32){
        #pragma unroll
        for (int q = 0; q < 2; q++){
            int iq = j + q * 16 + g;
            int cq = (iq < end) ? iq : beg;
            int s  = csrsrc[cq];
            if ((unsigned)s >= NN) s = 0;
            float e = el[s] + erd;
            e = (e >= 0.f) ? e : 0.2f * e;
            float w = (iq < end) ? __expf(e) : 0.f;
            float4 u = ftq[(unsigned)s * 4u + c];
            lsum += w;
            a0 += w * u.x; a1 += w * u.y; a2 += w * u.z; a3 += w * u.w;
        }
    }

    // Sum across the 16 groups (lane bits 2-5).
    #pragma unroll
    for (int off = 4; off < 64; off <<= 1){
        a0 += __shfl_xor(a0, off);
        a1 += __shfl_xor(a1, off);
        a2 += __shfl_xor(a2, off);
        a3 += __shfl_xor(a3, off);
        lsum += __shfl_xor(lsum, off);
    }

    if (lane < 4){
        float inv = (lsum > 0.f) ? 1.f / lsum : 0.f;
        float o0 = fmaxf(a0 * inv + ldf(bias, c * 4 + 0, isbf), 0.f);
        float o1 = fmaxf(a1 * inv + ldf(bias, c * 4 + 1, isbf), 0.f);
        float o2 = fmaxf(a2 * inv + ldf(bias, c * 4 + 2, isbf), 0.f);
        float o3 = fmaxf(a3 * inv + ldf(bias, c * 4 + 3, isbf), 0.f);
        if (isbf){
            uint2 pk;
            pk.x = (unsigned)f2bfu(o0) | ((unsigned)f2bfu(o1) << 16);
            pk.y = (unsigned)f2bfu(o2) | ((unsigned)f2bfu(o3) << 16);
            ((uint2*)outp)[n * 4 + c] = pk;
        } else {
            float4 o; o.x = o0; o.y = o1; o.z = o2; o.w = o3;
            ((float4*)outp)[n * 4 + c] = o;
        }
    }
}

// ---------------- host launch ----------------

static size_t align256(size_t x){ return (x + 255) & ~(size_t)255; }

extern "C" void kernel_launch(void* const* d_in, const int* in_sizes, int n_in,
                              void* d_out, int out_size, void* d_ws, size_t ws_size,
                              hipStream_t stream) {
    const void* feat = d_in[0];
    const int*  src  = (const int*)d_in[1];
    const int*  dst  = (const int*)d_in[2];
    const void* W1 = d_in[3];
    const void* al1= d_in[4];
    const void* ar1= d_in[5];
    const void* b1 = d_in[6];
    const void* W2 = d_in[7];
    const void* al2= d_in[8];
    const void* ar2= d_in[9];
    const void* b2 = d_in[10];
    const void* W3 = d_in[11];
    const void* al3= d_in[12];
    const void* ar3= d_in[13];
    const void* b3 = d_in[14];

    // workspace carve
    char* p = (char*)d_ws;
    size_t off = 0;
    auto carve = [&](size_t bytes)->void*{
        void* r = p + off;
        off += align256(bytes);
        return r;
    };
    float* ftA   = (float*)carve((size_t)NN * FF * 4);   // ft: pair-major bf16 (12.8MB) / f32 ft3 (layer 3); upper half = wcsr
    unsigned* hB = (unsigned*)carve((size_t)NN * FF * 4); // hidden state pair-major bf16; bpairs overlays pre-layer-1
    float* el    = (float*)carve((size_t)NN * 4);
    float* er    = (float*)carve((size_t)NN * 4);
    int*   rowptr= (int*)  carve((size_t)(NN + 1) * 4);
    int*   csrsrc= (int*)  carve((size_t)NE * 4);
    int*   bcounts=(int*)  carve((size_t)NB * 4);
    int*   bbase  =(int*)  carve((size_t)(NB + 1) * 4);
    int*   bh     =(int*)  carve((size_t)NB * NBLK * 4);  // per-(bucket,block) hist/offsets, 800KB
    unsigned short* wtg = (unsigned short*)carve((size_t)34816 * 2);  // W1t,W2t,W3t bf16
    int*   dflag  =(int*)  carve(256);
    unsigned* bpairs = (unsigned*)hB;   // overlay: consumed before hB is first written
    void*  ftb   = ftA;                 // pair-major bf16 ft view (layers 1-2); f32 ft3 view (layer 3)
    // wcsr overlays the UNUSED upper half of the ftA carve (layers 1-2 use only NN*FF*2 bytes).
    float* wcsr  = ftA + (size_t)NN * FF / 2;
    (void)ws_size; (void)n_in; (void)in_sizes; (void)out_size;

    dim3 b256(256);

    // fused prep: dtype detect + bcounts zero + weight transpose
    k_prep<<<dim3(136), b256, 0, stream>>>((const unsigned short*)feat, W1, W2, W3, dflag, bcounts, wtg);

    // CSR build via hierarchical counting sort
    k_bcount<<<dim3(NBLK), b256, 0, stream>>>(dst, bcounts, bh);
    k_bscan<<<dim3(1), b256, 0, stream>>>(bcounts, bbase, rowptr);
    k_boffset<<<dim3((NB + 3) / 4), b256, 0, stream>>>(bbase, bh);
    k_bucket<<<dim3(NBLK), b256, 0, stream>>>(src, dst, bh, bpairs);
    k_bsort<<<dim3(NB), b256, 0, stream>>>(bpairs, bbase, rowptr, csrsrc);

    const int mg_grid   = (NN + 63) / 64;     // 782
    const int node_grid = (NN + 3) / 4;       // 12500
    const int agg_grid  = node_grid * 4;      // 50000 (node-group x pair-slice)
    const int wn_grid   = (NN + 31) / 32;     // 1563

    // Layer 1: feat @ W1 -> ftP(pair-major bf16) + el/er; wnorm -> wcsr + er:=1/sum; sliced agg -> hB
    k_mgemm<0><<<dim3(mg_grid), b256, 0, stream>>>(feat, wtg, al1, ar1, dflag, (unsigned short*)ftb, el, er);
    k_wnorm<<<dim3(wn_grid), b256, 0, stream>>>(el, er, rowptr, csrsrc, wcsr);
    k_agg128<<<dim3(agg_grid), b256, 0, stream>>>((const unsigned*)ftb, rowptr, csrsrc, wcsr, er, b1, dflag, hB);

    // Layer 2: hP @ W2 -> ftP + el/er; wnorm; sliced agg -> hB
    k_mgemm<1><<<dim3(mg_grid), b256, 0, stream>>>(hB, wtg + 16384, al2, ar2, dflag, (unsigned short*)ftb, el, er);
    k_wnorm<<<dim3(wn_grid), b256, 0, stream>>>(el, er, rowptr, csrsrc, wcsr);
    k_agg128<<<dim3(agg_grid), b256, 0, stream>>>((const unsigned*)ftb, rowptr, csrsrc, wcsr, er, b2, dflag, hB);

    // Layer 3: hP @ W3 -> ft3(f32, node-major) + el/er; agg -> d_out (self-contained softmax)
    k_mgemm3<<<dim3(mg_grid), b256, 0, stream>>>(hB, wtg + 32768, al3, ar3, dflag, (float*)ftb, el, er);
    k_agg16<<<dim3(node_grid), b256, 0, stream>>>((const float*)ftb, el, er, rowptr, csrsrc, b3, dflag, d_out);
}

// Round 5
// 442.615 us; speedup vs baseline: 1.1690x; 1.1690x over previous
//
#include <hip/hip_runtime.h>
#include <hip/hip_bf16.h>

#define NN 50000
#define NE 1600000
#define FF 128
#define CC 16
#define NB ((NN + 63) / 64)       // 782 dst-buckets of 64 nodes
#define NBLK 256                  // partition blocks for the sort (all CUs)
#define CH ((NE + NBLK - 1) / NBLK)   // 6250 edges per partition block

using bf16 = __hip_bfloat16;
using bf16x8 = __attribute__((ext_vector_type(8))) short;   // 8 bf16 = 4 VGPRs
using f32x4  = __attribute__((ext_vector_type(4))) float;

// Runtime-dtype load: isbf selects bf16 vs f32 interpretation of p.
static __device__ __forceinline__ float ldf(const void* p, int i, int isbf){
    return isbf ? __bfloat162float(((const bf16*)p)[i]) : ((const float*)p)[i];
}
static __device__ __forceinline__ float bflo(unsigned u){
    union{unsigned x; float f;} c; c.x = u << 16; return c.f;
}
static __device__ __forceinline__ float bfhi(unsigned u){
    union{unsigned x; float f;} c; c.x = u & 0xFFFF0000u; return c.f;
}
static __device__ __forceinline__ unsigned short f2bfu(float v){
    bf16 b = __float2bfloat16(v);
    union{bf16 b; unsigned short u;} c; c.b = b; return c.u;
}

// ---------------- fused prep: dtype detect + bcounts zero + W1/W2/W3 transpose->bf16 ----------------
__global__ __launch_bounds__(256) void k_prep(const unsigned short* __restrict__ featu,
                                              const void* __restrict__ W1, const void* __restrict__ W2,
                                              const void* __restrict__ W3, int* __restrict__ dflag,
                                              int* __restrict__ bcounts, unsigned short* __restrict__ wtg){
    __shared__ int cnt;
    const int t = threadIdx.x;
    if (t == 0) cnt = 0;
    __syncthreads();
    unsigned short lo = featu[2 * t];
    int e = (lo >> 7) & 0xFF;
    if (e >= 117 && e <= 137) atomicAdd(&cnt, 1);
    __syncthreads();
    const int isbf = (cnt >= 128) ? 1 : 0;   // 1 => bf16 inputs
    int idx = blockIdx.x * 256 + t;
    if (idx == 0) *dflag = isbf;
    if (idx < NB) bcounts[idx] = 0;
    if (idx < 32768){
        int l = idx >> 14;                   // 0: W1, 1: W2
        int e2 = idx & 16383;
        int f = e2 >> 7, k = e2 & 127;
        const void* W = l ? W2 : W1;
        wtg[idx] = f2bfu(ldf(W, k * FF + f, isbf));
    } else if (idx < 34816){
        int e2 = idx - 32768;                // W3t: 16x128
        int f = e2 >> 7, k = e2 & 127;
        wtg[idx] = f2bfu(ldf(W3, k * CC + f, isbf));
    }
}

// ---------------- CSR build: hierarchical counting sort by dst ----------------

__global__ __launch_bounds__(256) void k_bcount(const int* __restrict__ dst, int* __restrict__ bcounts,
                                                int* __restrict__ bh){
    __shared__ int hist[NB];
    const int t = threadIdx.x, b = blockIdx.x;
    for (int i = t; i < NB; i += 256) hist[i] = 0;
    __syncthreads();
    const int beg = b * CH, end = (beg + CH < NE) ? beg + CH : NE;
    for (int i = beg + t; i < end; i += 256){
        int d = dst[i];
        if ((unsigned)d >= NN) d = 0;
        atomicAdd(&hist[d >> 6], 1);
    }
    __syncthreads();
    for (int k = t; k < NB; k += 256){
        int v = hist[k];
        bh[k * NBLK + b] = v;
        if (v) atomicAdd(&bcounts[k], v);
    }
}

__global__ __launch_bounds__(256) void k_bscan(const int* __restrict__ bcounts, int* __restrict__ bbase,
                                               int* __restrict__ rowptr){
    __shared__ int s[256];
    const int t = threadIdx.x;
    constexpr int PT = (NB + 255) / 256;   // 4
    int loc[PT];
    int sum = 0;
    #pragma unroll
    for (int i = 0; i < PT; i++){
        int idx = t * PT + i;
        int v = (idx < NB) ? bcounts[idx] : 0;
        loc[i] = sum;
        sum += v;
    }
    s[t] = sum; __syncthreads();
    for (int off = 1; off < 256; off <<= 1){
        int x = (t >= off) ? s[t - off] : 0;
        __syncthreads();
        s[t] += x;
        __syncthreads();
    }
    int base = (t > 0) ? s[t - 1] : 0;
    #pragma unroll
    for (int i = 0; i < PT; i++){
        int idx = t * PT + i;
        if (idx < NB) bbase[idx] = base + loc[i];
    }
    if (t == 255){
        bbase[NB] = s[255];      // == NE
        rowptr[NN] = s[255];
    }
}

// Per-bucket offsets: wave-per-bucket shfl scan over the 256 per-block counts (4/lane).
__global__ __launch_bounds__(256) void k_boffset(const int* __restrict__ bbase, int* __restrict__ bh){
    int k = blockIdx.x * 4 + (threadIdx.x >> 6);
    int lane = threadIdx.x & 63;
    if (k >= NB) return;
    int v[4];
    int s = 0;
    #pragma unroll
    for (int i = 0; i < 4; i++){
        v[i] = bh[k * NBLK + 4 * lane + i];
        s += v[i];
    }
    int tot = s;
    #pragma unroll
    for (int off = 1; off < 64; off <<= 1){
        int x = __shfl_up(s, off);
        if (lane >= off) s += x;
    }
    int run = bbase[k] + s - tot;   // exclusive prefix of per-lane sums
    #pragma unroll
    for (int i = 0; i < 4; i++){
        bh[k * NBLK + 4 * lane + i] = run;
        run += v[i];
    }
}

__global__ __launch_bounds__(256) void k_bucket(const int* __restrict__ src, const int* __restrict__ dst,
                                                const int* __restrict__ bh, unsigned* __restrict__ bpairs){
    __shared__ int cur[NB];
    const int t = threadIdx.x, b = blockIdx.x;
    for (int k = t; k < NB; k += 256) cur[k] = bh[k * NBLK + b];
    __syncthreads();
    const int beg = b * CH, end = (beg + CH < NE) ? beg + CH : NE;
    for (int i = beg + t; i < end; i += 256){
        int s = src[i];
        int d = dst[i];
        if ((unsigned)s >= NN) s = 0;
        if ((unsigned)d >= NN) d = 0;
        int p = atomicAdd(&cur[d >> 6], 1);
        if ((unsigned)p < NE) bpairs[p] = (unsigned)s | ((unsigned)(d & 63) << 16);
    }
}

__global__ __launch_bounds__(256) void k_bsort(const unsigned* __restrict__ bpairs, const int* __restrict__ bbase,
                                               int* __restrict__ rowptr, int* __restrict__ csrsrc){
    __shared__ int cnt[64];
    __shared__ int cur[64];
    const int t = threadIdx.x;
    const int b = blockIdx.x;
    const int base = bbase[b];
    const int endb = bbase[b + 1];
    if (t < 64) cnt[t] = 0;
    __syncthreads();
    for (int i = base + t; i < endb; i += 256)
        atomicAdd(&cnt[bpairs[i] >> 16], 1);
    __syncthreads();
    if (t < 64){   // wave 0 exactly: 64-lane exclusive scan via shfl
        int v = cnt[t];
        int inc = v;
        #pragma unroll
        for (int off = 1; off < 64; off <<= 1){
            int x = __shfl_up(inc, off);
            if (t >= off) inc += x;
        }
        int excl = inc - v;
        cur[t] = excl;
        int d = b * 64 + t;
        if (d < NN) rowptr[d] = base + excl;
    }
    __syncthreads();
    for (int i = base + t; i < endb; i += 256){
        unsigned pr = bpairs[i];
        int p = atomicAdd(&cur[pr >> 16], 1);
        csrsrc[base + p] = (int)(pr & 0xFFFFu);
    }
}

// ---------------- MFMA GEMM (layers 1-2), LDS-FREE ----------------
// MODE 0: layer-1 — X is node-major input feat (f32 or bf16 per dflag).
// MODE 1: layer-2 — X is pair-major bf16 hidden state hP[p][node][32].
// Output ft is written PAIR-MAJOR: ftP[p][node][32] (p = feature-pair slice 0..3),
// so the sliced aggregation kernel gets a contiguous 64B row-slice per (p, node).

template<int MODE>
__global__ __launch_bounds__(256) void k_mgemm(const void* __restrict__ X, const unsigned short* __restrict__ wtg,
                                               const void* __restrict__ al, const void* __restrict__ ar,
                                               const int* __restrict__ dflag, unsigned short* __restrict__ ftP,
                                               float* __restrict__ el, float* __restrict__ er){
    const int isbf = *dflag;
    const int t  = threadIdx.x;
    const int n0 = blockIdx.x * 64;
    const int wv = t >> 6;
    const int lane = t & 63;
    const int quad = lane >> 4;
    const int mcol = lane & 15;
    const int row = n0 + wv * 16 + mcol;
    const int rc  = (row < NN) ? row : 0;   // clamped A row

    bf16x8 afr[4];
    if (MODE == 0 && !isbf){
        const float* xr = (const float*)X + rc * FF + quad * 8;
        #pragma unroll
        for (int kt = 0; kt < 4; kt++){
            float4 a = *(const float4*)(xr + kt * 32);
            float4 b = *(const float4*)(xr + kt * 32 + 4);
            union { bf16x8 v; unsigned u[4]; } c;
            c.u[0] = (unsigned)f2bfu(a.x) | ((unsigned)f2bfu(a.y) << 16);
            c.u[1] = (unsigned)f2bfu(a.z) | ((unsigned)f2bfu(a.w) << 16);
            c.u[2] = (unsigned)f2bfu(b.x) | ((unsigned)f2bfu(b.y) << 16);
            c.u[3] = (unsigned)f2bfu(b.z) | ((unsigned)f2bfu(b.w) << 16);
            afr[kt] = c.v;
        }
    } else if (MODE == 0){
        const unsigned short* xr = (const unsigned short*)X + rc * FF + quad * 8;
        #pragma unroll
        for (int kt = 0; kt < 4; kt++)
            afr[kt] = *(const bf16x8*)(xr + kt * 32);
    } else {
        // pair-major bf16: feats q8..q8+7 live at hP[(q8>>5)][rc][q8&31]
        #pragma unroll
        for (int kt = 0; kt < 4; kt++){
            int q8 = quad * 8 + kt * 32;
            const unsigned short* xr = (const unsigned short*)X + ((size_t)(q8 >> 5) * NN + rc) * 32 + (q8 & 31);
            afr[kt] = *(const bf16x8*)xr;
        }
    }

    float elp[4] = {0.f,0.f,0.f,0.f}, erp[4] = {0.f,0.f,0.f,0.f};

    #pragma unroll
    for (int f = 0; f < 8; f++){
        f32x4 acc = {0.f, 0.f, 0.f, 0.f};
        const unsigned short* wr = wtg + (f * 16 + mcol) * FF + quad * 8;
        #pragma unroll
        for (int kt = 0; kt < 4; kt++){
            bf16x8 bfr = *(const bf16x8*)(wr + kt * 32);
            acc = __builtin_amdgcn_mfma_f32_16x16x32_bf16(afr[kt], bfr, acc, 0, 0, 0);
        }
        int col = f * 16 + mcol;
        float alv = ldf(al, col, isbf);
        float arv = ldf(ar, col, isbf);
        #pragma unroll
        for (int reg = 0; reg < 4; reg++){
            int node = n0 + wv * 16 + quad * 4 + reg;
            float v = acc[reg];
            if (node < NN)
                ftP[((size_t)(f >> 1) * NN + node) * 32 + (f & 1) * 16 + mcol] = f2bfu(v);
            elp[reg] += v * alv;
            erp[reg] += v * arv;
        }
    }

    #pragma unroll
    for (int reg = 0; reg < 4; reg++){
        float pl = elp[reg], pr = erp[reg];
        #pragma unroll
        for (int off = 1; off < 16; off <<= 1){
            pl += __shfl_xor(pl, off);
            pr += __shfl_xor(pr, off);
        }
        int node = n0 + wv * 16 + quad * 4 + reg;
        if (mcol == 0 && node < NN){ el[node] = pl; er[node] = pr; }
    }
}

// ---------------- MFMA GEMM (layer 3): ft3 = hP(pair-major bf16) @ W3, f32 node-major out ----------------

__global__ __launch_bounds__(256) void k_mgemm3(const void* __restrict__ X, const unsigned short* __restrict__ wt3g,
                                                const void* __restrict__ al, const void* __restrict__ ar,
                                                const int* __restrict__ dflag, float* __restrict__ ft,
                                                float* __restrict__ el, float* __restrict__ er){
    const int isbf = *dflag;
    const int t  = threadIdx.x;
    const int n0 = blockIdx.x * 64;
    const int wv = t >> 6;
    const int lane = t & 63;
    const int quad = lane >> 4;
    const int mcol = lane & 15;
    const int row = n0 + wv * 16 + mcol;
    const int rc  = (row < NN) ? row : 0;

    const unsigned short* wr = wt3g + mcol * FF + quad * 8;

    f32x4 acc = {0.f, 0.f, 0.f, 0.f};
    #pragma unroll
    for (int kt = 0; kt < 4; kt++){
        int q8 = quad * 8 + kt * 32;
        const unsigned short* xr = (const unsigned short*)X + ((size_t)(q8 >> 5) * NN + rc) * 32 + (q8 & 31);
        bf16x8 afr = *(const bf16x8*)xr;
        bf16x8 bfr = *(const bf16x8*)(wr + kt * 32);
        acc = __builtin_amdgcn_mfma_f32_16x16x32_bf16(afr, bfr, acc, 0, 0, 0);
    }

    float alv = ldf(al, mcol, isbf);
    float arv = ldf(ar, mcol, isbf);
    #pragma unroll
    for (int reg = 0; reg < 4; reg++){
        int node = n0 + wv * 16 + quad * 4 + reg;
        float v = acc[reg];
        if (node < NN) ft[node * CC + mcol] = v;
        float pl = v * alv, pr = v * arv;
        #pragma unroll
        for (int off = 1; off < 16; off <<= 1){
            pl += __shfl_xor(pl, off);
            pr += __shfl_xor(pr, off);
        }
        if (mcol == 0 && node < NN){ el[node] = pl; er[node] = pr; }
    }
}

// ---------------- Weight prepass: edata[e] = {src, exp(leaky(el[src]+er[dst]))} (8B packed), ----------------
// ---------------- per-node inv-sum written back into er[n]. 8 lanes per node. ----------------

__global__ __launch_bounds__(256) void k_wnorm(const float* __restrict__ el, float* __restrict__ er,
                                               const int* __restrict__ rowptr, const int* __restrict__ csrsrc,
                                               uint2* __restrict__ edata){
    const int t = threadIdx.x;
    const int n = blockIdx.x * 32 + (t >> 3);
    if (n >= NN) return;
    const int sub = t & 7;
    int beg = rowptr[n], end = rowptr[n + 1];
    beg = (beg < 0) ? 0 : (beg > NE ? NE : beg);
    end = (end < beg) ? beg : (end > NE ? NE : end);
    const float erd = er[n];
    float sum = 0.f;
    for (int i = beg + sub; i < end; i += 8){
        int s = csrsrc[i];
        if ((unsigned)s >= NN) s = 0;
        float e = el[s] + erd;
        e = (e >= 0.f) ? e : 0.2f * e;
        float ex = __expf(e);
        uint2 d; d.x = (unsigned)s; d.y = __float_as_uint(ex);
        edata[i] = d;
        sum += ex;
    }
    sum += __shfl_xor(sum, 1);
    sum += __shfl_xor(sum, 2);
    sum += __shfl_xor(sum, 4);
    if (sub == 0) er[n] = 1.f / ((sum > 0.f) ? sum : 1.f);
}

// ---------------- Sliced aggregation (128 feats, pair-major bf16 ft), dwordx4 gather ----------------
// Each block handles ONE 32-feature pair-slice (p = blockIdx&3) for 4 dst nodes (grp = blockIdx>>2).
// p = blockIdx&3 and xcd = blockIdx%8 => each XCD serves exactly one slice (3.2MB, L2-resident);
// confirmed by R4: FETCH_SIZE 151->57MB. This round restores R1's issue efficiency on top:
// g = lane>>2 picks one of 16 edges per sub-batch, c = lane&3 picks the 16B chunk of the 64B
// slice-row -> one dwordx4 moves 16 edges x 16B = 1KB/instr (4x R4). (src,w) comes as one 8B
// edata record (halves index instrs vs csrsrc+wcsr). 32 edges (2 gathers) in flight per iter.

__global__ __launch_bounds__(256) void k_agg128(const uint4* __restrict__ ftq, const int* __restrict__ rowptr,
                                                const uint2* __restrict__ edata, const float* __restrict__ erinv,
                                                const void* __restrict__ bias, const int* __restrict__ dflag,
                                                uint4* __restrict__ outP){
    const int isbf = *dflag;
    const int p   = blockIdx.x & 3;           // feature-pair slice (32 feats)
    const int grp = blockIdx.x >> 2;          // node group of 4
    const int lane = threadIdx.x & 63;
    const int n = grp * 4 + (threadIdx.x >> 6);
    if (n >= NN) return;
    int beg = rowptr[n], end = rowptr[n + 1];
    beg = (beg < 0) ? 0 : (beg > NE ? NE : beg);
    end = (end < beg) ? beg : (end > NE ? NE : end);

    const int g = lane >> 2;                  // edge slot 0..15
    const int c = lane & 3;                   // uint4 index within 64B slice-row
    const uint4* fp = ftq + (size_t)p * NN * 4;   // 4 uint4 (64B) per node
    float acc[8] = {0.f,0.f,0.f,0.f,0.f,0.f,0.f,0.f};

    for (int j = beg; j < end; j += 32){
        int iq0 = j + g;
        int iq1 = j + 16 + g;
        int cq0 = (iq0 < end) ? iq0 : beg;
        int cq1 = (iq1 < end) ? iq1 : beg;
        uint2 d0 = edata[cq0];
        uint2 d1 = edata[cq1];
        unsigned s0 = d0.x; if (s0 >= NN) s0 = 0;
        unsigned s1 = d1.x; if (s1 >= NN) s1 = 0;
        float w0 = (iq0 < end) ? __uint_as_float(d0.y) : 0.f;
        float w1 = (iq1 < end) ? __uint_as_float(d1.y) : 0.f;
        uint4 u0 = fp[s0 * 4u + c];
        uint4 u1 = fp[s1 * 4u + c];
        acc[0] += w0 * bflo(u0.x); acc[1] += w0 * bfhi(u0.x);
        acc[2] += w0 * bflo(u0.y); acc[3] += w0 * bfhi(u0.y);
        acc[4] += w0 * bflo(u0.z); acc[5] += w0 * bfhi(u0.z);
        acc[6] += w0 * bflo(u0.w); acc[7] += w0 * bfhi(u0.w);
        acc[0] += w1 * bflo(u1.x); acc[1] += w1 * bfhi(u1.x);
        acc[2] += w1 * bflo(u1.y); acc[3] += w1 * bfhi(u1.y);
        acc[4] += w1 * bflo(u1.z); acc[5] += w1 * bfhi(u1.z);
        acc[6] += w1 * bflo(u1.w); acc[7] += w1 * bfhi(u1.w);
    }

    // Sum across the 16 edge-groups (lane bits 2-5).
    #pragma unroll
    for (int k = 0; k < 8; k++){
        acc[k] += __shfl_xor(acc[k], 4);
        acc[k] += __shfl_xor(acc[k], 8);
        acc[k] += __shfl_xor(acc[k], 16);
        acc[k] += __shfl_xor(acc[k], 32);
    }

    if (g == 0){
        float inv = erinv[n];
        int fcol = p * 32 + c * 8;            // 8 feats per lane
        float o[8];
        #pragma unroll
        for (int k = 0; k < 8; k++)
            o[k] = fmaxf(acc[k] * inv + ldf(bias, fcol + k, isbf), 0.f);
        uint4 pk;
        pk.x = (unsigned)f2bfu(o[0]) | ((unsigned)f2bfu(o[1]) << 16);
        pk.y = (unsigned)f2bfu(o[2]) | ((unsigned)f2bfu(o[3]) << 16);
        pk.z = (unsigned)f2bfu(o[4]) | ((unsigned)f2bfu(o[5]) << 16);
        pk.w = (unsigned)f2bfu(o[6]) | ((unsigned)f2bfu(o[7]) << 16);
        outP[((size_t)p * NN + n) * 4u + c] = pk;
    }
}

// ---------------- Aggregation (16 feats, f32 ft): single-pass gather with inline softmax ----------------
// Footprint 3.2MB (L2-resident per XCD); g = lane>>2 picks one of 16 edges, c = lane&3 the float4.

__global__ __launch_bounds__(256) void k_agg16(const float* __restrict__ ftv, const float* __restrict__ el,
                                               const float* __restrict__ er, const int* __restrict__ rowptr,
                                               const int* __restrict__ csrsrc, const void* __restrict__ bias,
                                               const int* __restrict__ dflag, void* __restrict__ outp){
    const int isbf = *dflag;
    const int lane = threadIdx.x & 63;
    const int n = blockIdx.x * 4 + (threadIdx.x >> 6);
    if (n >= NN) return;
    int beg = rowptr[n], end = rowptr[n + 1];
    beg = (beg < 0) ? 0 : (beg > NE ? NE : beg);
    end = (end < beg) ? beg : (end > NE ? NE : end);
    const float erd = er[n];

    const int g = lane >> 2;     // edge slot 0..15
    const int c = lane & 3;      // float4 index within 64B row
    const float4* ftq = (const float4*)ftv;
    float a0 = 0.f, a1 = 0.f, a2 = 0.f, a3 = 0.f;
    float lsum = 0.f;

    for (int j = beg; j < end; j += 32){
        #pragma unroll
        for (int q = 0; q < 2; q++){
            int iq = j + q * 16 + g;
            int cq = (iq < end) ? iq : beg;
            int s  = csrsrc[cq];
            if ((unsigned)s >= NN) s = 0;
            float e = el[s] + erd;
            e = (e >= 0.f) ? e : 0.2f * e;
            float w = (iq < end) ? __expf(e) : 0.f;
            float4 u = ftq[(unsigned)s * 4u + c];
            lsum += w;
            a0 += w * u.x; a1 += w * u.y; a2 += w * u.z; a3 += w * u.w;
        }
    }

    // Sum across the 16 groups (lane bits 2-5).
    #pragma unroll
    for (int off = 4; off < 64; off <<= 1){
        a0 += __shfl_xor(a0, off);
        a1 += __shfl_xor(a1, off);
        a2 += __shfl_xor(a2, off);
        a3 += __shfl_xor(a3, off);
        lsum += __shfl_xor(lsum, off);
    }

    if (lane < 4){
        float inv = (lsum > 0.f) ? 1.f / lsum : 0.f;
        float o0 = fmaxf(a0 * inv + ldf(bias, c * 4 + 0, isbf), 0.f);
        float o1 = fmaxf(a1 * inv + ldf(bias, c * 4 + 1, isbf), 0.f);
        float o2 = fmaxf(a2 * inv + ldf(bias, c * 4 + 2, isbf), 0.f);
        float o3 = fmaxf(a3 * inv + ldf(bias, c * 4 + 3, isbf), 0.f);
        if (isbf){
            uint2 pk;
            pk.x = (unsigned)f2bfu(o0) | ((unsigned)f2bfu(o1) << 16);
            pk.y = (unsigned)f2bfu(o2) | ((unsigned)f2bfu(o3) << 16);
            ((uint2*)outp)[n * 4 + c] = pk;
        } else {
            float4 o; o.x = o0; o.y = o1; o.z = o2; o.w = o3;
            ((float4*)outp)[n * 4 + c] = o;
        }
    }
}

// ---------------- host launch ----------------

static size_t align256(size_t x){ return (x + 255) & ~(size_t)255; }

extern "C" void kernel_launch(void* const* d_in, const int* in_sizes, int n_in,
                              void* d_out, int out_size, void* d_ws, size_t ws_size,
                              hipStream_t stream) {
    const void* feat = d_in[0];
    const int*  src  = (const int*)d_in[1];
    const int*  dst  = (const int*)d_in[2];
    const void* W1 = d_in[3];
    const void* al1= d_in[4];
    const void* ar1= d_in[5];
    const void* b1 = d_in[6];
    const void* W2 = d_in[7];
    const void* al2= d_in[8];
    const void* ar2= d_in[9];
    const void* b2 = d_in[10];
    const void* W3 = d_in[11];
    const void* al3= d_in[12];
    const void* ar3= d_in[13];
    const void* b3 = d_in[14];

    // workspace carve
    char* p = (char*)d_ws;
    size_t off = 0;
    auto carve = [&](size_t bytes)->void*{
        void* r = p + off;
        off += align256(bytes);
        return r;
    };
    float* ftA   = (float*)carve((size_t)NN * FF * 4);   // ft: pair-major bf16 (12.8MB) / f32 ft3 (layer 3); upper half = edata
    unsigned* hB = (unsigned*)carve((size_t)NN * FF * 4); // hidden state pair-major bf16; bpairs overlays pre-layer-1
    float* el    = (float*)carve((size_t)NN * 4);
    float* er    = (float*)carve((size_t)NN * 4);
    int*   rowptr= (int*)  carve((size_t)(NN + 1) * 4);
    int*   csrsrc= (int*)  carve((size_t)NE * 4);
    int*   bcounts=(int*)  carve((size_t)NB * 4);
    int*   bbase  =(int*)  carve((size_t)(NB + 1) * 4);
    int*   bh     =(int*)  carve((size_t)NB * NBLK * 4);  // per-(bucket,block) hist/offsets, 800KB
    unsigned short* wtg = (unsigned short*)carve((size_t)34816 * 2);  // W1t,W2t,W3t bf16
    int*   dflag  =(int*)  carve(256);
    unsigned* bpairs = (unsigned*)hB;   // overlay: consumed before hB is first written
    void*  ftb   = ftA;                 // pair-major bf16 ft view (layers 1-2); f32 ft3 view (layer 3)
    // edata (8B x NE = 12.8MB) overlays the UNUSED upper half of the ftA carve
    // (layers 1-2 use only NN*FF*2 = 12.8MB of the 25.6MB carve; layer 3 uses 3.2MB, no edata).
    uint2* edata = (uint2*)(ftA + (size_t)NN * FF / 2);
    (void)ws_size; (void)n_in; (void)in_sizes; (void)out_size;

    dim3 b256(256);

    // fused prep: dtype detect + bcounts zero + weight transpose
    k_prep<<<dim3(136), b256, 0, stream>>>((const unsigned short*)feat, W1, W2, W3, dflag, bcounts, wtg);

    // CSR build via hierarchical counting sort
    k_bcount<<<dim3(NBLK), b256, 0, stream>>>(dst, bcounts, bh);
    k_bscan<<<dim3(1), b256, 0, stream>>>(bcounts, bbase, rowptr);
    k_boffset<<<dim3((NB + 3) / 4), b256, 0, stream>>>(bbase, bh);
    k_bucket<<<dim3(NBLK), b256, 0, stream>>>(src, dst, bh, bpairs);
    k_bsort<<<dim3(NB), b256, 0, stream>>>(bpairs, bbase, rowptr, csrsrc);

    const int mg_grid   = (NN + 63) / 64;     // 782
    const int node_grid = (NN + 3) / 4;       // 12500
    const int agg_grid  = node_grid * 4;      // 50000 (node-group x pair-slice)
    const int wn_grid   = (NN + 31) / 32;     // 1563

    // Layer 1: feat @ W1 -> ftP(pair-major bf16) + el/er; wnorm -> edata + er:=1/sum; sliced agg -> hB
    k_mgemm<0><<<dim3(mg_grid), b256, 0, stream>>>(feat, wtg, al1, ar1, dflag, (unsigned short*)ftb, el, er);
    k_wnorm<<<dim3(wn_grid), b256, 0, stream>>>(el, er, rowptr, csrsrc, edata);
    k_agg128<<<dim3(agg_grid), b256, 0, stream>>>((const uint4*)ftb, rowptr, edata, er, b1, dflag, (uint4*)hB);

    // Layer 2: hP @ W2 -> ftP + el/er; wnorm; sliced agg -> hB
    k_mgemm<1><<<dim3(mg_grid), b256, 0, stream>>>(hB, wtg + 16384, al2, ar2, dflag, (unsigned short*)ftb, el, er);
    k_wnorm<<<dim3(wn_grid), b256, 0, stream>>>(el, er, rowptr, csrsrc, edata);
    k_agg128<<<dim3(agg_grid), b256, 0, stream>>>((const uint4*)ftb, rowptr, edata, er, b2, dflag, (uint4*)hB);

    // Layer 3: hP @ W3 -> ft3(f32, node-major) + el/er; agg -> d_out (self-contained softmax)
    k_mgemm3<<<dim3(mg_grid), b256, 0, stream>>>(hB, wtg + 32768, al3, ar3, dflag, (float*)ftb, el, er);
    k_agg16<<<dim3(node_grid), b256, 0, stream>>>((const float*)ftb, el, er, rowptr, csrsrc, b3, dflag, d_out);
}